// Round 5
// baseline (170.019 us; speedup 1.0000x reference)
//
#include <hip/hip_runtime.h>
#include <hip/hip_bf16.h>
#include <math.h>

#define SEQ_LEN  8192
#define HIDDEN   1024
#define NUM_SPANS 4096
#define MAX_W    32
#define NEG_INF  -1e9f

__device__ __forceinline__ float dot4(float4 a, float4 b) {
    return a.x * b.x + a.y * b.y + a.z * b.z + a.w * b.w;
}

// One block (256 threads = 4 waves) per span. Flash-style single pass over the
// span rows in chunks of 4, SINGLE-buffered LDS + register-held prefetch:
//   - wave w owns row w of the chunk: 64 lanes load the 4 KB row coalesced
//     (4x float4, lane stride 16 B), dot against attn_w held in registers,
//     butterfly-reduce -> score.
//   - next chunk's rows live in registers across the consume, so only ONE
//     16 KB LDS buffer is needed: read buf -> barrier -> stage -> (accumulate
//     math overlaps staging) -> barrier.
// R4 evidence: 33 KB double buffer capped residency at ~2.5 blocks/CU
// (Occupancy 31%) and left HBM at 47%. 16.4 KB + launch_bounds(256,8) doubles
// resident waves (VGPR was 52, cap 64 -> no spill).
__global__ __launch_bounds__(256, 8) void span_repr_kernel(
    const float* __restrict__ emb,      // (SEQ_LEN, HIDDEN)
    const int* __restrict__ starts,     // (NUM_SPANS,)
    const int* __restrict__ ends,       // (NUM_SPANS,)
    const float* __restrict__ attn_w,   // (HIDDEN,)
    const float* __restrict__ attn_b,   // (1,)
    float* __restrict__ out)            // (NUM_SPANS, 3*HIDDEN)
{
    const int s   = blockIdx.x;
    const int tid = threadIdx.x;
    const int w2  = tid >> 6;    // wave id 0..3  == row-in-chunk
    const int c   = tid & 63;    // lane  0..63

    __shared__ float4 buf[4][256];      // 16 KB, single-buffered
    __shared__ float  cscore[2][4];     // scores double-buffered (tiny)

    const int start = starts[s];
    const int end   = ends[s];
    const int wmax  = end - start;      // inclusive width-1, 0..31
    const float bias = attn_b[0];

    const float4* __restrict__ embr = (const float4*)emb;

    // prefetch start/end rows (latency hidden behind preamble)
    float4 sv = embr[(size_t)start * 256 + tid];
    float4 ev = embr[(size_t)end   * 256 + tid];

    // per-lane attn_w slice: float4 indices c, c+64, c+128, c+192
    const float4* __restrict__ wv4 = (const float4*)attn_w;
    const float4 wv0 = wv4[c];
    const float4 wv1 = wv4[c + 64];
    const float4 wv2 = wv4[c + 128];
    const float4 wv3 = wv4[c + 192];

    const int nc = (wmax >> 2) + 1;     // chunks of 4 rows: 1..8

    // ---------------- preamble: stage chunk 0 + its score -----------------
    {
        const int r  = w2;
        const int rc = min(r, wmax);             // clamp: dup of end row, wt=0
        const float4* __restrict__ row = embr + (size_t)(start + rc) * 256;
        float4 r0 = row[c];
        float4 r1 = row[c + 64];
        float4 r2 = row[c + 128];
        float4 r3 = row[c + 192];
        float p = dot4(r0, wv0) + dot4(r1, wv1) + dot4(r2, wv2) + dot4(r3, wv3);
        #pragma unroll
        for (int off = 32; off > 0; off >>= 1)
            p += __shfl_xor(p, off, 64);
        if (c == 0) cscore[0][w2] = (r <= wmax) ? (p + bias) : NEG_INF;
        buf[w2][c]       = r0;
        buf[w2][c + 64]  = r1;
        buf[w2][c + 128] = r2;
        buf[w2][c + 192] = r3;
    }

    // write start/end rows while the preamble drains
    float4* __restrict__ out4 = (float4*)(out + (size_t)s * (3 * HIDDEN));
    out4[tid]       = sv;
    out4[256 + tid] = ev;

    __syncthreads();

    float4 acc = make_float4(0.f, 0.f, 0.f, 0.f);
    float m = -INFINITY;
    float l = 0.0f;

    for (int ck = 0; ck < nc; ++ck) {
        const int par = ck & 1;
        const int pn  = par ^ 1;
        const bool more = (ck + 1 < nc);

        // -------- issue next chunk's global loads (stay in registers) -----
        float4 r0, r1, r2, r3;
        if (more) {
            const int r  = (ck + 1) * 4 + w2;
            const int rc = min(r, wmax);
            const float4* __restrict__ row = embr + (size_t)(start + rc) * 256;
            r0 = row[c];
            r1 = row[c + 64];
            r2 = row[c + 128];
            r3 = row[c + 192];
        }

        // -------- pull chunk ck out of LDS into registers -----------------
        const float s0 = cscore[par][0];
        const float s1 = cscore[par][1];
        const float s2 = cscore[par][2];
        const float s3 = cscore[par][3];
        const float4 b0 = buf[0][tid];
        const float4 b1 = buf[1][tid];
        const float4 b2 = buf[2][tid];
        const float4 b3 = buf[3][tid];

        __syncthreads();   // everyone finished READING buf

        // -------- score + stage the prefetched chunk ----------------------
        if (more) {
            float p = dot4(r0, wv0) + dot4(r1, wv1) + dot4(r2, wv2) + dot4(r3, wv3);
            #pragma unroll
            for (int off = 32; off > 0; off >>= 1)
                p += __shfl_xor(p, off, 64);
            const int r = (ck + 1) * 4 + w2;
            if (c == 0) cscore[pn][w2] = (r <= wmax) ? (p + bias) : NEG_INF;
            buf[w2][c]       = r0;
            buf[w2][c + 64]  = r1;
            buf[w2][c + 128] = r2;
            buf[w2][c + 192] = r3;
        }

        // -------- online softmax + weighted accumulate (no buf dep; -------
        // -------- overlaps the staging writes above) ----------------------
        const float cm = fmaxf(fmaxf(s0, s1), fmaxf(s2, s3));
        const float mn = fmaxf(m, cm);
        const float alpha = __expf(m - mn);      // m=-inf first chunk -> 0
        const float e0 = __expf(s0 - mn);        // masked (-1e9) -> exactly 0
        const float e1 = __expf(s1 - mn);
        const float e2 = __expf(s2 - mn);
        const float e3 = __expf(s3 - mn);
        l = l * alpha + (e0 + e1 + e2 + e3);
        acc.x = acc.x * alpha + e0 * b0.x + e1 * b1.x + e2 * b2.x + e3 * b3.x;
        acc.y = acc.y * alpha + e0 * b0.y + e1 * b1.y + e2 * b2.y + e3 * b3.y;
        acc.z = acc.z * alpha + e0 * b0.z + e1 * b1.z + e2 * b2.z + e3 * b3.z;
        acc.w = acc.w * alpha + e0 * b0.w + e1 * b1.w + e2 * b2.w + e3 * b3.w;
        m = mn;

        __syncthreads();   // staging complete
    }

    const float inv = 1.0f / l;                  // row 0 always valid -> l > 0
    out4[512 + tid] = make_float4(acc.x * inv, acc.y * inv,
                                  acc.z * inv, acc.w * inv);
}

extern "C" void kernel_launch(void* const* d_in, const int* in_sizes, int n_in,
                              void* d_out, int out_size, void* d_ws, size_t ws_size,
                              hipStream_t stream) {
    const float* emb    = (const float*)d_in[0];
    const int*   starts = (const int*)d_in[1];
    const int*   ends   = (const int*)d_in[2];
    const float* attn_w = (const float*)d_in[3];
    const float* attn_b = (const float*)d_in[4];
    float* out = (float*)d_out;

    span_repr_kernel<<<NUM_SPANS, 256, 0, stream>>>(emb, starts, ends, attn_w, attn_b, out);
}

// Round 6
// 126.727 us; speedup vs baseline: 1.3416x; 1.3416x over previous
//
#include <hip/hip_runtime.h>
#include <hip/hip_bf16.h>
#include <math.h>

#define SEQ_LEN  8192
#define HIDDEN   1024
#define NUM_SPANS 4096
#define MAX_W    32
#define NEG_INF  -1e9f

__device__ __forceinline__ float dot4(float4 a, float4 b) {
    return a.x * b.x + a.y * b.y + a.z * b.z + a.w * b.w;
}

// One block (256 threads = 4 waves) per span. Flash-style single pass in
// chunks of 4 rows, single 16 KB LDS buffer, register-held prefetch.
// Liveness-minimized loop order (R5 post-mortem: holding b0..b3 AND r0..r3
// live together under a 64-VGPR cap spilled float4s to scratch, +150 MB HBM):
//   issue loads r -> read buf b -> accumulate (b dies) -> barrier
//   -> score+stage r (r dies) -> barrier.
// launch_bounds(256,4): R4-proven no-spill budget (cap 128); with 16.9 KB LDS
// and ~52 VGPRs the HW can still reach 8 blocks/CU.
__global__ __launch_bounds__(256, 4) void span_repr_kernel(
    const float* __restrict__ emb,      // (SEQ_LEN, HIDDEN)
    const int* __restrict__ starts,     // (NUM_SPANS,)
    const int* __restrict__ ends,       // (NUM_SPANS,)
    const float* __restrict__ attn_w,   // (HIDDEN,)
    const float* __restrict__ attn_b,   // (1,)
    float* __restrict__ out)            // (NUM_SPANS, 3*HIDDEN)
{
    const int s   = blockIdx.x;
    const int tid = threadIdx.x;
    const int w2  = tid >> 6;    // wave id 0..3  == row-in-chunk
    const int c   = tid & 63;    // lane  0..63

    __shared__ float4 buf[4][256];      // 16 KB, single-buffered
    __shared__ float  cscore[2][4];     // scores double-buffered (tiny)

    const int start = starts[s];
    const int end   = ends[s];
    const int wmax  = end - start;      // inclusive width-1, 0..31
    const float bias = attn_b[0];

    const float4* __restrict__ embr = (const float4*)emb;

    // prefetch start/end rows (latency hidden behind preamble)
    float4 sv = embr[(size_t)start * 256 + tid];
    float4 ev = embr[(size_t)end   * 256 + tid];

    // per-lane attn_w slice: float4 indices c, c+64, c+128, c+192
    const float4* __restrict__ wv4 = (const float4*)attn_w;
    const float4 wv0 = wv4[c];
    const float4 wv1 = wv4[c + 64];
    const float4 wv2 = wv4[c + 128];
    const float4 wv3 = wv4[c + 192];

    const int nc = (wmax >> 2) + 1;     // chunks of 4 rows: 1..8

    // ---------------- preamble: stage chunk 0 + its score -----------------
    {
        const int r  = w2;
        const int rc = min(r, wmax);             // clamp: dup of end row, wt=0
        const float4* __restrict__ row = embr + (size_t)(start + rc) * 256;
        float4 r0 = row[c];
        float4 r1 = row[c + 64];
        float4 r2 = row[c + 128];
        float4 r3 = row[c + 192];
        float p = dot4(r0, wv0) + dot4(r1, wv1) + dot4(r2, wv2) + dot4(r3, wv3);
        #pragma unroll
        for (int off = 32; off > 0; off >>= 1)
            p += __shfl_xor(p, off, 64);
        if (c == 0) cscore[0][w2] = (r <= wmax) ? (p + bias) : NEG_INF;
        buf[w2][c]       = r0;
        buf[w2][c + 64]  = r1;
        buf[w2][c + 128] = r2;
        buf[w2][c + 192] = r3;
    }

    // write start/end rows while the preamble drains
    float4* __restrict__ out4 = (float4*)(out + (size_t)s * (3 * HIDDEN));
    out4[tid]       = sv;
    out4[256 + tid] = ev;

    __syncthreads();

    float4 acc = make_float4(0.f, 0.f, 0.f, 0.f);
    float m = -INFINITY;
    float l = 0.0f;

    for (int ck = 0; ck < nc; ++ck) {
        const int par = ck & 1;
        const int pn  = par ^ 1;
        const bool more = (ck + 1 < nc);

        // -------- issue next chunk's global loads (stay in flight through
        // -------- the LDS reads + accumulate + barrier below) -------------
        float4 r0, r1, r2, r3;
        if (more) {
            const int r  = (ck + 1) * 4 + w2;
            const int rc = min(r, wmax);
            const float4* __restrict__ row = embr + (size_t)(start + rc) * 256;
            r0 = row[c];
            r1 = row[c + 64];
            r2 = row[c + 128];
            r3 = row[c + 192];
        }

        // -------- consume chunk ck: LDS reads then accumulate (b dies) ----
        const float s0 = cscore[par][0];
        const float s1 = cscore[par][1];
        const float s2 = cscore[par][2];
        const float s3 = cscore[par][3];
        const float4 b0 = buf[0][tid];
        const float4 b1 = buf[1][tid];
        const float4 b2 = buf[2][tid];
        const float4 b3 = buf[3][tid];

        const float cm = fmaxf(fmaxf(s0, s1), fmaxf(s2, s3));
        const float mn = fmaxf(m, cm);
        const float alpha = __expf(m - mn);      // m=-inf first chunk -> 0
        const float e0 = __expf(s0 - mn);        // masked (-1e9) -> exactly 0
        const float e1 = __expf(s1 - mn);
        const float e2 = __expf(s2 - mn);
        const float e3 = __expf(s3 - mn);
        l = l * alpha + (e0 + e1 + e2 + e3);
        acc.x = acc.x * alpha + e0 * b0.x + e1 * b1.x + e2 * b2.x + e3 * b3.x;
        acc.y = acc.y * alpha + e0 * b0.y + e1 * b1.y + e2 * b2.y + e3 * b3.y;
        acc.z = acc.z * alpha + e0 * b0.z + e1 * b1.z + e2 * b2.z + e3 * b3.z;
        acc.w = acc.w * alpha + e0 * b0.w + e1 * b1.w + e2 * b2.w + e3 * b3.w;
        m = mn;

        __syncthreads();   // everyone finished READING buf

        // -------- score + stage the prefetched chunk (r dies) -------------
        if (more) {
            float p = dot4(r0, wv0) + dot4(r1, wv1) + dot4(r2, wv2) + dot4(r3, wv3);
            #pragma unroll
            for (int off = 32; off > 0; off >>= 1)
                p += __shfl_xor(p, off, 64);
            const int r = (ck + 1) * 4 + w2;
            if (c == 0) cscore[pn][w2] = (r <= wmax) ? (p + bias) : NEG_INF;
            buf[w2][c]       = r0;
            buf[w2][c + 64]  = r1;
            buf[w2][c + 128] = r2;
            buf[w2][c + 192] = r3;
        }
        __syncthreads();   // staging complete
    }

    const float inv = 1.0f / l;                  // row 0 always valid -> l > 0
    out4[512 + tid] = make_float4(acc.x * inv, acc.y * inv,
                                  acc.z * inv, acc.w * inv);
}

extern "C" void kernel_launch(void* const* d_in, const int* in_sizes, int n_in,
                              void* d_out, int out_size, void* d_ws, size_t ws_size,
                              hipStream_t stream) {
    const float* emb    = (const float*)d_in[0];
    const int*   starts = (const int*)d_in[1];
    const int*   ends   = (const int*)d_in[2];
    const float* attn_w = (const float*)d_in[3];
    const float* attn_b = (const float*)d_in[4];
    float* out = (float*)d_out;

    span_repr_kernel<<<NUM_SPANS, 256, 0, stream>>>(emb, starts, ends, attn_w, attn_b, out);
}